// Round 2
// baseline (1030.245 us; speedup 1.0000x reference)
//
#include <hip/hip_runtime.h>
#include <cstdint>
#include <cstddef>

// RIMCell forward, MI355X.
//  Full-batch: wtrans (weights->f16 (N,K), self-padding), xconv, fused fp32 q/kx
//  GEMM (top-k critical -> exact fp32), vx = x@Wv (f16 MFMA), s0, mask/alpha.
//  Then (single chunk if ws allows): inputs build, preact GEMM (f16 out), LSTM,
//  comm GEMM (f16 out), attention, ctx@Wco GEMM (f16 out), epilogue.
// Output d_out = [hs_out (B,6,600) | cs_out (B,6,600)] fp32.
//
// R1: BK=64, double-buffered LDS, XOR swizzle -> bank conflicts 0, but preact
//     GEMM unchanged at 201us: both R0/R1 ride a ~9.3 TB/s L2/L3 staged-traffic
//     ceiling (nothing on-CU is busy: Mfma 26%, VALU 19%, HBM 18%).
// R2: halve staged traffic: BM=256 tiles (512 thr, 8 waves 2x4, wave-tile
//     128x64, BK=64, 128KiB dbuf LDS) for preact/comm; 256x128 for ctxW
//     (N=640 exact). XCD-aware flat-bid swizzle so M-blocks sharing a W panel
//     colocate per XCD L2. Weight buffers N-padded (W1T 2560, W2T 2816 rows),
//     C stores column-guarded; activation layouts unchanged.

typedef _Float16 f16;
typedef _Float16 f16x8 __attribute__((ext_vector_type(8)));
typedef float    f32x4 __attribute__((ext_vector_type(4)));

__device__ __forceinline__ void async16(const void* g, void* l) {
    __builtin_amdgcn_global_load_lds((const __attribute__((address_space(1))) void*)g,
                                     (__attribute__((address_space(3))) void*)l,
                                     16, 0, 0);
}

// ---------------- big MFMA f16 GEMM: C[M,N] = A[M,K] * W^T, W stored (N,K) ----
// BM=256 fixed (grid.x=M/256), BN in {128,256} (grid.y=ceil(N/BN), W rows padded
// to grid.y*BN), K%64==0, W row pitch == K. 512 threads = 8 waves (WM x WN).
// Double-buffered 64-wide K tiles, XOR-swizzled LDS, XCD-aware block swizzle.
template <typename CT, int BN, int WM, int WN>
__global__ __launch_bounds__(512, 2)
void mfma_gemm2(const f16* __restrict__ A, const f16* __restrict__ W,
                CT* __restrict__ C, int K, int lda, int ldc, int Nreal,
                long sAu, long sWu, long sCu)
{
    constexpr int MI = 256 / WM / 16;    // m-fragments per wave
    const int gx = gridDim.x, gy = gridDim.y;
    int bid = blockIdx.x + gx * (blockIdx.y + gy * blockIdx.z);
    const int nwg = gx * gy * gridDim.z;
    if ((nwg & 7) == 0)                  // XCD swizzle (bijective when nwg%8==0)
        bid = (bid & 7) * (nwg >> 3) + (bid >> 3);
    const int bx  = bid % gx;
    const int byz = bid / gx;
    const int by  = byz % gy;
    const int bz  = byz / gy;
    A += (long)bz * sAu;
    W += (long)bz * sWu;
    C += (long)bz * sCu;
    const int tm = bx * 256;
    const int tn = by * BN;

    __shared__ __attribute__((aligned(16))) f16 As[2][256 * 64];
    __shared__ __attribute__((aligned(16))) f16 Ws[2][BN * 64];

    const int tid  = threadIdx.x;
    const int wave = tid >> 6;
    const int lane = tid & 63;
    const int wm = (wave / WN) * (256 / WM);
    const int wn = (wave % WN) * (BN / WN);
    // staging: each async16 covers 8 rows x 64 halves (1KB); lane -> (row, 16B chunk)
    const int srow = lane >> 3;
    const int scol = ((lane & 7) ^ srow) * 8;      // pre-swizzled global col (halves)
    // fragment roles
    const int mrow = lane & 15;
    const int kq   = (lane >> 4) * 8;
    const int swz  = (mrow & 7) << 3;

    f32x4 acc[MI][4] = {};

    auto stage = [&](int b, int kk) {
#pragma unroll
        for (int t = 0; t < 4; t++) {              // A: 256 rows
            const int rb = t * 64 + wave * 8;      // wave-uniform LDS base
            async16(A + (long)(tm + rb + srow) * lda + (kk + scol), &As[b][rb * 64]);
        }
#pragma unroll
        for (int t = 0; t < BN / 64; t++) {        // W: BN rows
            const int rb = t * 64 + wave * 8;
            async16(W + (long)(tn + rb + srow) * K + (kk + scol), &Ws[b][rb * 64]);
        }
    };
    auto compute = [&](int b) {
#pragma unroll
        for (int c = 0; c < 2; c++) {              // two k=32 chunks of the 64-tile
            const int cc = (c * 32 + kq) ^ swz;
            f16x8 aF[MI], wF[4];
#pragma unroll
            for (int i = 0; i < MI; i++)
                aF[i] = *(const f16x8*)&As[b][(wm + i * 16 + mrow) * 64 + cc];
#pragma unroll
            for (int j = 0; j < 4; j++)
                wF[j] = *(const f16x8*)&Ws[b][(wn + j * 16 + mrow) * 64 + cc];
#pragma unroll
            for (int i = 0; i < MI; i++)
#pragma unroll
                for (int j = 0; j < 4; j++)
                    acc[i][j] = __builtin_amdgcn_mfma_f32_16x16x32_f16(aF[i], wF[j], acc[i][j], 0, 0, 0);
        }
    };

    stage(0, 0);
    int bsel = 0;
    const int nk = K >> 6;
    for (int s = 0; s < nk; s++) {
        __syncthreads();                 // compiler drains own vmcnt -> tile bsel ready
        if (s + 1 < nk) stage(bsel ^ 1, (s + 1) << 6);   // prefetch hides under compute
        compute(bsel);
        bsel ^= 1;
    }
    const int rrow = (lane >> 4) * 4;   // C/D: col = lane&15, row = (lane>>4)*4 + r
#pragma unroll
    for (int i = 0; i < MI; i++)
#pragma unroll
        for (int j = 0; j < 4; j++) {
            const int col = tn + wn + j * 16 + mrow;
            if (col < Nreal)
#pragma unroll
                for (int r = 0; r < 4; r++)
                    C[(long)(tm + wm + i * 16 + rrow + r) * ldc + col] = (CT)acc[i][j][r];
        }
}

// ---------------- small MFMA f16 GEMM (vx only): 128x128 tiles, 256 thr -------
template <typename CT>
__global__ __launch_bounds__(256)
void mfma_gemm(const f16* __restrict__ A, const f16* __restrict__ W,
               CT* __restrict__ C, int K, int lda, int ldc,
               long sAu, long sWu, long sCu)
{
    A += (long)blockIdx.z * sAu;
    W += (long)blockIdx.z * sWu;
    C += (long)blockIdx.z * sCu;
    const int tm = blockIdx.x * 128;
    const int tn = blockIdx.y * 128;
    __shared__ __attribute__((aligned(16))) f16 As[2][128 * 64];
    __shared__ __attribute__((aligned(16))) f16 Ws[2][128 * 64];
    const int tid  = threadIdx.x;
    const int wave = tid >> 6;
    const int lane = tid & 63;
    const int wm = (wave >> 1) * 64;
    const int wn = (wave & 1) * 64;
    const int srow = lane >> 3;
    const int scol = ((lane & 7) ^ srow) * 8;
    const int mrow = lane & 15;
    const int kq   = (lane >> 4) * 8;
    const int swz  = (mrow & 7) << 3;

    f32x4 acc[4][4] = {};

    auto stage = [&](int b, int kk) {
#pragma unroll
        for (int t = 0; t < 4; t++) {
            const int rbase = t * 32 + wave * 8;
            async16(A + (long)(tm + rbase + srow) * lda + (kk + scol), &As[b][rbase * 64]);
            async16(W + (long)(tn + rbase + srow) * K   + (kk + scol), &Ws[b][rbase * 64]);
        }
    };
    auto compute = [&](int b) {
#pragma unroll
        for (int c = 0; c < 2; c++) {
            const int cc = (c * 32 + kq) ^ swz;
            f16x8 aF[4], wF[4];
#pragma unroll
            for (int i = 0; i < 4; i++)
                aF[i] = *(const f16x8*)&As[b][(wm + i * 16 + mrow) * 64 + cc];
#pragma unroll
            for (int j = 0; j < 4; j++)
                wF[j] = *(const f16x8*)&Ws[b][(wn + j * 16 + mrow) * 64 + cc];
#pragma unroll
            for (int i = 0; i < 4; i++)
#pragma unroll
                for (int j = 0; j < 4; j++)
                    acc[i][j] = __builtin_amdgcn_mfma_f32_16x16x32_f16(aF[i], wF[j], acc[i][j], 0, 0, 0);
        }
    };

    stage(0, 0);
    int bsel = 0;
    const int nk = K >> 6;
    for (int s = 0; s < nk; s++) {
        __syncthreads();
        if (s + 1 < nk) stage(bsel ^ 1, (s + 1) << 6);
        compute(bsel);
        bsel ^= 1;
    }
    const int rrow = (lane >> 4) * 4;
#pragma unroll
    for (int i = 0; i < 4; i++)
#pragma unroll
        for (int j = 0; j < 4; j++)
#pragma unroll
            for (int r = 0; r < 4; r++)
                C[(long)(tm + wm + i * 16 + rrow + r) * ldc + (tn + wn + j * 16 + mrow)] = (CT)acc[i][j][r];
}

// ---------------- fused fp32 GEMM (top-k critical): q = hs@Wq (z<6), kx = x@Wk (z==6)
__global__ __launch_bounds__(256)
void sgemm_fused(const float* __restrict__ hs, const float* __restrict__ Wq,
                 const float* __restrict__ x, const float* __restrict__ Wk,
                 float* __restrict__ q, float* __restrict__ kx)
{
    const int z = blockIdx.z;
    const float* A; const float* W; float* C; int lda, ldc;
    if (z < 6) { A = hs + z * 600; W = Wq + (long)z * 38400; C = q + z * 64; lda = 3600; ldc = 384; }
    else       { A = x;            W = Wk;                   C = kx;         lda = 600;  ldc = 64;  }
    const int K = 600;
    const int tm = blockIdx.x * 64;
    __shared__ __attribute__((aligned(16))) float AsT[16][64];   // k-major
    __shared__ __attribute__((aligned(16))) float Ws[16][64];
    const int t = threadIdx.x;
    const int arow = t >> 2, akc = (t & 3) * 4;
    const int wkw = t >> 4, wn = (t & 15) * 4;
    const int tx = t & 15, ty = t >> 4;

    float4 aR, wR;
    const float* Arow = A + (long)(tm + arow) * lda;
    auto loadA = [&](int kk) {
        const int k0 = kk + akc;
        const float* p = Arow + k0;
        if (k0 + 3 < K) aR = *(const float4*)p;
        else {
            aR.x = (k0 + 0 < K) ? p[0] : 0.f; aR.y = (k0 + 1 < K) ? p[1] : 0.f;
            aR.z = (k0 + 2 < K) ? p[2] : 0.f; aR.w = (k0 + 3 < K) ? p[3] : 0.f;
        }
    };
    auto loadW = [&](int kk) {
        const int k = kk + wkw;
        if (k < K) wR = *(const float4*)(W + (long)k * 64 + wn);
        else       wR = float4{0.f, 0.f, 0.f, 0.f};
    };
    loadA(0); loadW(0);
    float acc[4][4] = {{0.f}};
    const int NS = 38;
    for (int s = 0; s < NS; s++) {
        __syncthreads();
        AsT[akc + 0][arow] = aR.x; AsT[akc + 1][arow] = aR.y;
        AsT[akc + 2][arow] = aR.z; AsT[akc + 3][arow] = aR.w;
        *(float4*)&Ws[wkw][wn] = wR;
        __syncthreads();
        if (s + 1 < NS) { loadA((s + 1) * 16); loadW((s + 1) * 16); }
#pragma unroll
        for (int k = 0; k < 16; k++) {
            const float4 av = *(const float4*)&AsT[k][ty * 4];
            const float4 wv = *(const float4*)&Ws[k][tx * 4];
            acc[0][0] += av.x * wv.x; acc[0][1] += av.x * wv.y; acc[0][2] += av.x * wv.z; acc[0][3] += av.x * wv.w;
            acc[1][0] += av.y * wv.x; acc[1][1] += av.y * wv.y; acc[1][2] += av.y * wv.z; acc[1][3] += av.y * wv.w;
            acc[2][0] += av.z * wv.x; acc[2][1] += av.z * wv.y; acc[2][2] += av.z * wv.z; acc[2][3] += av.z * wv.w;
            acc[3][0] += av.w * wv.x; acc[3][1] += av.w * wv.y; acc[3][2] += av.w * wv.z; acc[3][3] += av.w * wv.w;
        }
    }
#pragma unroll
    for (int r = 0; r < 4; r++)
#pragma unroll
        for (int c = 0; c < 4; c++)
            C[(long)(tm + ty * 4 + r) * ldc + tx * 4 + c] = acc[r][c];
}

// -------- weight transpose+convert with self-padding:
// dst[n*ldd + k] = (f16)src[k*N + n] for k<K,n<N; 0 for K<=k<Kp or N<=n<Np.
__global__ __launch_bounds__(256)
void wtrans(const float* __restrict__ src, f16* __restrict__ dst,
            int K, int N, int Kp, int Np, int ldd, long sSrc, long sDst)
{
    src += (long)blockIdx.z * sSrc;
    dst += (long)blockIdx.z * sDst;
    __shared__ float tile[32][33];
    const int tK = blockIdx.x * 32, tN = blockIdx.y * 32;
    const int tx = threadIdx.x & 31, ty = threadIdx.x >> 5;
#pragma unroll
    for (int i = 0; i < 4; i++) {
        const int k = tK + ty + i * 8, n = tN + tx;
        tile[ty + i * 8][tx] = (k < K && n < N) ? src[(long)k * N + n] : 0.f;
    }
    __syncthreads();
#pragma unroll
    for (int i = 0; i < 4; i++) {
        const int n = tN + ty + i * 8, k = tK + tx;
        if (n < Np && k < Kp) dst[(long)n * ldd + k] = (f16)tile[tx][ty + i * 8];
    }
}

// ---------------- elementwise kernels -----------------------------------------
__global__ void xconv_kernel(const float* __restrict__ x, f16* __restrict__ xf, long n)
{
    const long i = (long)blockIdx.x * 256 + threadIdx.x;
    if (i >= n) return;
    const long b = i / 640;
    const int c = (int)(i - b * 640);
    xf[i] = (f16)(c < 600 ? x[b * 600 + c] : 0.f);
}

__global__ void s0_kernel(const float* __restrict__ q, const float* __restrict__ kx,
                          float* __restrict__ s0, int n)
{
    const int i = blockIdx.x * 256 + threadIdx.x;
    if (i >= n) return;
    const int b = i / 6;
    const float* qp = q + (long)i * 64;
    const float* kp = kx + (long)b * 64;
    float s = 0.f;
#pragma unroll
    for (int k = 0; k < 64; k++) s += qp[k] * kp[k];
    s0[i] = s * 0.125f;    // / sqrt(64)
}

__global__ void mask_kernel(const float* __restrict__ s0, float* __restrict__ mask,
                            float* __restrict__ alpha, int Bc)
{
    const int b = blockIdx.x * 256 + threadIdx.x;
    if (b >= Bc) return;
    float v[6];
#pragma unroll
    for (int u = 0; u < 6; u++) v[u] = s0[b * 6 + u];
#pragma unroll
    for (int u = 0; u < 6; u++) {
        int rank = 0;
#pragma unroll
        for (int m = 0; m < 6; m++)
            rank += ((v[m] > v[u]) || (v[m] == v[u] && m < u)) ? 1 : 0;   // stable top-k
        const float mk = (rank < 4) ? 1.f : 0.f;
        mask[b * 6 + u] = mk;
        alpha[b * 6 + u] = mk / (1.f + __expf(-v[u]));
    }
}

__global__ void inputs_kernel(const float* __restrict__ vx, const float* __restrict__ hs,
                              const float* __restrict__ alpha, f16* __restrict__ icat, long n)
{   // icat (b,u,1024) = [alpha*vx(400) | hs(600) | 0(24)]
    const long i = (long)blockIdx.x * 256 + threadIdx.x;
    if (i >= n) return;
    const int k = (int)(i & 1023);
    const long bu = i >> 10;
    float v;
    if (k < 400)       v = alpha[bu] * vx[(bu / 6) * 512 + k];
    else if (k < 1000) v = hs[bu * 600 + (k - 400)];
    else               v = 0.f;
    icat[i] = (f16)v;
}

__device__ __forceinline__ float tanh_fast(float x) {
    x = fminf(20.f, fmaxf(-20.f, x));
    const float e = __expf(2.f * x);
    return (e - 1.f) / (e + 1.f);
}

__global__ void lstm_kernel(const f16* __restrict__ pre, const float* __restrict__ cs,
                            const float* __restrict__ mask, float* __restrict__ cs_out,
                            f16* __restrict__ hbf, long n)   // n = Bc*6*640
{
    const long i = (long)blockIdx.x * 256 + threadIdx.x;
    if (i >= n) return;
    const long bu = i / 640;
    const int h = (int)(i - bu * 640);
    if (h >= 600) { hbf[i] = (f16)0.f; return; }   // zero K-pad for next GEMM
    const f16* p = pre + bu * 2432;
    const float ig = 1.f / (1.f + __expf(-(float)p[h]));
    const float fg = 1.f / (1.f + __expf(-(float)p[600 + h]));
    const float og = 1.f / (1.f + __expf(-(float)p[1200 + h]));
    const float g  = tanh_fast((float)p[1800 + h]);
    const float cold = cs[bu * 600 + h];
    const float c = cold * fg + ig * g;
    cs_out[bu * 600 + h] = (mask[bu] != 0.f) ? c : cold;
    hbf[i] = (f16)(og * tanh_fast(c));
}

__global__ __launch_bounds__(256)
void attn_kernel(const f16* __restrict__ out2, const float* __restrict__ mask,
                 f16* __restrict__ ctx)
{   // out2 (b,m,2688) f16: [cv 0:2400 | ck 2400:2528 | cq 2528:2656 | pad]
    // ctx (b,u,2432): cols [2400,2432) zero-filled (K-pad for ctx@Wco GEMM)
    const long b = blockIdx.x;
    __shared__ float sck[6][128];
    __shared__ float scq[6][128];
    __shared__ float sp[4][6][6];
    const int t = threadIdx.x;
#pragma unroll
    for (int m = 0; m < 6; m++) {
        const f16* row = out2 + (b * 6 + m) * 2688;
        if (t < 128) sck[m][t] = (float)row[2400 + t];
        else         scq[m][t - 128] = (float)row[2528 + (t - 128)];
    }
    __syncthreads();
    if (t < 144) {
        const int h = t / 36, u = (t / 6) % 6, m = t % 6;
        float s = 0.f;
#pragma unroll
        for (int k = 0; k < 32; k++) s += scq[u][h * 32 + k] * sck[m][h * 32 + k];
        sp[h][u][m] = s * 0.1767766952966369f;   // 1/sqrt(32)
    }
    __syncthreads();
    if (t < 24) {
        const int h = t / 6, u = t % 6;
        float mx = sp[h][u][0];
#pragma unroll
        for (int m = 1; m < 6; m++) mx = fmaxf(mx, sp[h][u][m]);
        float e[6], sum = 0.f;
#pragma unroll
        for (int m = 0; m < 6; m++) { e[m] = __expf(sp[h][u][m] - mx); sum += e[m]; }
        const float sc = mask[b * 6 + u] / sum;
#pragma unroll
        for (int m = 0; m < 6; m++) sp[h][u][m] = e[m] * sc;
    }
    __syncthreads();
    for (int f = t; f < 2432; f += 256) {
        if (f < 2400) {
            const int h = f / 600;
            float cv[6];
#pragma unroll
            for (int m = 0; m < 6; m++) cv[m] = (float)out2[(b * 6 + m) * 2688 + f];
#pragma unroll
            for (int u = 0; u < 6; u++) {
                float s = 0.f;
#pragma unroll
                for (int m = 0; m < 6; m++) s += sp[h][u][m] * cv[m];
                ctx[(b * 6 + u) * 2432 + f] = (f16)s;
            }
        } else {
#pragma unroll
            for (int u = 0; u < 6; u++) ctx[(b * 6 + u) * 2432 + f] = (f16)0.f;
        }
    }
}

__global__ void epi_kernel(const f16* __restrict__ ctxW, const f16* __restrict__ hbf,
                           const float* __restrict__ hs, const float* __restrict__ mask,
                           float* __restrict__ hs_out, long n)   // n = Bc*3600
{
    const long i = (long)blockIdx.x * 256 + threadIdx.x;
    if (i >= n) return;
    const long bu = i / 600;
    const int h = (int)(i - bu * 600);
    hs_out[i] = (mask[bu] != 0.f) ? ((float)ctxW[bu * 640 + h] + (float)hbf[bu * 640 + h]) : hs[i];
}

// ---------------- host launcher ------------------------------------------------
static inline unsigned cdivu(long a, long b) { return (unsigned)((a + b - 1) / b); }

extern "C" void kernel_launch(void* const* d_in, const int* in_sizes, int n_in,
                              void* d_out, int out_size, void* d_ws, size_t ws_size,
                              hipStream_t stream)
{
    (void)in_sizes; (void)n_in; (void)out_size;
    const float* x    = (const float*)d_in[0];
    const float* hs   = (const float*)d_in[1];
    const float* cs   = (const float*)d_in[2];
    const float* Wk   = (const float*)d_in[3];
    const float* Wv   = (const float*)d_in[4];
    const float* Wq   = (const float*)d_in[5];
    const float* Wi2h = (const float*)d_in[6];
    const float* Wh2h = (const float*)d_in[7];
    const float* Wck  = (const float*)d_in[8];
    const float* Wcq  = (const float*)d_in[9];
    const float* Wcv  = (const float*)d_in[10];
    const float* Wco  = (const float*)d_in[11];
    float* hs_out = (float*)d_out;
    float* cs_out = hs_out + (long)4096 * 6 * 600;

    char* wsb = (char*)d_ws;
    size_t off = 0;
    auto alloc = [&](size_t bytes) -> char* {
        char* p = wsb + off;
        off += (bytes + 255) & ~(size_t)255;
        return p;
    };

    // f16 weights, (N,K) transposed, N padded to tile grid, K padded to x64:
    // W1T (2560,1024) [Wi2h;Wh2h], W2T (2816,640) [Wcv|Wck|Wcq|pad],
    // W3T (640,2432) [Wco], WvT (512,640) [Wv]
    f16* W1T = (f16*)alloc((size_t)6 * 2560 * 1024 * 2);
    f16* W2T = (f16*)alloc((size_t)6 * 2816 * 640 * 2);
    f16* W3T = (f16*)alloc((size_t)6 * 640 * 2432 * 2);
    f16* WvT = (f16*)alloc((size_t)512 * 640 * 2);

    // full-batch buffers (B=4096)
    f16*   xf   = (f16*)  alloc((size_t)4096 * 640 * 2);
    float* kx   = (float*)alloc((size_t)4096 * 64 * 4);
    float* vx   = (float*)alloc((size_t)4096 * 512 * 4);
    float* q    = (float*)alloc((size_t)4096 * 384 * 4);
    float* s0   = (float*)alloc((size_t)4096 * 6 * 4);
    float* alph = (float*)alloc((size_t)4096 * 6 * 4);
    float* mskv = (float*)alloc((size_t)4096 * 6 * 4);
    const size_t fixedbytes = off;

    // per-chunk activations (all f16):
    // perRow = icat 12288 + pre 29184 + hbf 7680 + out2 32256 = 81408 B
    const size_t perRow = 81408;
    int Bc = 4096;
    while (Bc > 256 && fixedbytes + (size_t)Bc * perRow + 16384 > ws_size) Bc >>= 1;

    f16* icat = (f16*)alloc((size_t)Bc * 6 * 1024 * 2);
    f16* pre  = (f16*)alloc((size_t)Bc * 6 * 2432 * 2);
    f16* hbf  = (f16*)alloc((size_t)Bc * 6 * 640 * 2);
    f16* out2 = (f16*)alloc((size_t)Bc * 6 * 2688 * 2);
    // overlays: ctx over dead pre (after LSTM); ctxW over dead out2 (after attn)
    f16* ctx  = pre;    // needs Bc*6*2432*2 <= Bc*6*2432*2  ok (exact)
    f16* ctxW = out2;   // needs Bc*6*640*2  <= Bc*6*2688*2  ok

    // ---- weights: transpose-convert with self-padding (no memset needed) ----
    wtrans<<<dim3(13, 80, 6), 256, 0, stream>>>(Wi2h, W1T,        400, 2400, 400, 2560, 1024, 960000L,  2621440L);
    wtrans<<<dim3(20, 80, 6), 256, 0, stream>>>(Wh2h, W1T + 400,  600, 2400, 624, 2560, 1024, 1440000L, 2621440L);
    wtrans<<<dim3(20, 75, 6), 256, 0, stream>>>(Wcv,  W2T,        600, 2400, 640, 2400, 640,  1440000L, 1802240L);
    wtrans<<<dim3(20, 4, 6),  256, 0, stream>>>(Wck,  W2T + (long)2400 * 640, 600, 128, 640, 128, 640, 76800L, 1802240L);
    wtrans<<<dim3(20, 9, 6),  256, 0, stream>>>(Wcq,  W2T + (long)2528 * 640, 600, 128, 640, 288, 640, 76800L, 1802240L);
    wtrans<<<dim3(76, 20, 6), 256, 0, stream>>>(Wco,  W3T,        2400, 600, 2432, 640, 2432, 1440000L, 1556480L);
    wtrans<<<dim3(20, 16, 1), 256, 0, stream>>>(Wv,   WvT,        600,  400, 640, 512, 640,  0L, 0L);

    // ---- full-batch score path (exact fp32 where top-k depends on it) ----
    xconv_kernel<<<cdivu((long)4096 * 640, 256), 256, 0, stream>>>(x, xf, (long)4096 * 640);
    sgemm_fused<<<dim3(64, 1, 7), 256, 0, stream>>>(hs, Wq, x, Wk, q, kx);
    mfma_gemm<float><<<dim3(32, 4, 1), 256, 0, stream>>>(xf, WvT, vx, 640, 640, 512, 0, 0, 0);
    s0_kernel<<<cdivu((long)4096 * 6, 256), 256, 0, stream>>>(q, kx, s0, 4096 * 6);
    mask_kernel<<<cdivu(4096, 256), 256, 0, stream>>>(s0, mskv, alph, 4096);

    for (int b0 = 0; b0 < 4096; b0 += Bc) {
        const float* hsc = hs + (long)b0 * 3600;
        const float* csc = cs + (long)b0 * 3600;
        float* hso = hs_out + (long)b0 * 3600;
        float* cso = cs_out + (long)b0 * 3600;

        inputs_kernel<<<cdivu((long)Bc * 6144, 256), 256, 0, stream>>>(
            vx + (long)b0 * 512, hsc, alph + (long)b0 * 6, icat, (long)Bc * 6144);
        // preact = [a*vx|hs] @ [Wi2h;Wh2h]   (f16 out), N 2432 padded to 2560
        mfma_gemm2<f16, 256, 2, 4><<<dim3(Bc / 256, 10, 6), 512, 0, stream>>>(
            icat, W1T, pre, 1024, 6144, 14592, 2432, 1024, 2621440, 2432);
        lstm_kernel<<<cdivu((long)Bc * 3840, 256), 256, 0, stream>>>(
            pre, csc, mskv + (long)b0 * 6, cso, hbf, (long)Bc * 3840);
        // [cv|ck|cq] = h @ [Wcv|Wck|Wcq]   (f16 out), N 2688 padded to 2816
        mfma_gemm2<f16, 256, 2, 4><<<dim3(Bc / 256, 11, 6), 512, 0, stream>>>(
            hbf, W2T, out2, 640, 3840, 16128, 2688, 640, 1802240, 2688);
        attn_kernel<<<Bc, 256, 0, stream>>>(out2, mskv + (long)b0 * 6, ctx);
        // ctxW = ctx @ Wco   (f16 out), N=640 exact with BN=128
        mfma_gemm2<f16, 128, 4, 2><<<dim3(Bc / 256, 5, 6), 512, 0, stream>>>(
            ctx, W3T, ctxW, 2432, 14592, 3840, 640, 2432, 1556480, 640);
        epi_kernel<<<cdivu((long)Bc * 3600, 256), 256, 0, stream>>>(
            ctxW, hbf, hsc, mskv + (long)b0 * 6, hso, (long)Bc * 3600);
    }
}

// Round 4
// 996.830 us; speedup vs baseline: 1.0335x; 1.0335x over previous
//
#include <hip/hip_runtime.h>
#include <cstdint>
#include <cstddef>

// RIMCell forward, MI355X.
//  Full-batch: wtrans (weights->f16 (N,K), self-padding), xconv, fused fp32 q/kx
//  GEMM (top-k critical -> exact fp32), vx = x@Wv (f16 MFMA), s0, mask/alpha.
//  Then (single chunk if ws allows): inputs build, preact GEMM (f16 out), LSTM,
//  comm GEMM (f16 out), attention, ctx@Wco GEMM (f16 out), epilogue.
// Output d_out = [hs_out (B,6,600) | cs_out (B,6,600)] fp32.
//
// R1: BK=64 dbuf + XOR swizzle -> conflicts 0, time unchanged (regime gate).
// R2: 256-wide tiles halved staged traffic -> time unchanged (185us): 2-phase
//     structural stall (Mfma 29 + VALU 19 = 48% busy), not bandwidth.
// R3: 8-phase counted-vmcnt schedule (T3+T4+T5) for preact/comm. Container
//     failed twice (infra push times were 3500s+; schedule audit clean).
// R4: resubmit R3 hardened: __builtin_amdgcn_s_barrier() for barriers,
//     sched_barrier(0) after every inline-asm waitcnt (rule #18).

typedef _Float16 f16;
typedef _Float16 f16x8 __attribute__((ext_vector_type(8)));
typedef float    f32x4 __attribute__((ext_vector_type(4)));

__device__ __forceinline__ void async16(const void* g, void* l) {
    __builtin_amdgcn_global_load_lds((const __attribute__((address_space(1))) void*)g,
                                     (__attribute__((address_space(3))) void*)l,
                                     16, 0, 0);
}

__device__ __forceinline__ void BAR() { __builtin_amdgcn_s_barrier(); }
__device__ __forceinline__ void VMW2() {
    asm volatile("s_waitcnt vmcnt(2)" ::: "memory");
    __builtin_amdgcn_sched_barrier(0);
}
__device__ __forceinline__ void VMW0() {
    asm volatile("s_waitcnt vmcnt(0)" ::: "memory");
    __builtin_amdgcn_sched_barrier(0);
}

// ------------- 8-phase MFMA f16 GEMM: C[M,N] = A[M,K] * W^T, W stored (N,K) ---
// BM=256 (grid.x=M/256), BN=256 (grid.y=ceil(N/256), W rows padded), K%64==0,
// W row pitch == K. 512 threads = 8 waves (2M x 4N), wave-tile 128x64.
// Double-buffered BK=64 tiles (128 KiB LDS), XOR swizzle, XCD block swizzle.
// Schedule: per K-tile 4 phases (chunk c x i-half); each phase overlaps
// ds_read + one half-tile stage of tile t+1 with the previous phase's MFMA;
// counted vmcnt(2) once per K-tile (never 0 in main loop); setprio around
// each 16-MFMA cluster.
template <typename CT>
__global__ __launch_bounds__(512, 2)
void mfma_gemm8(const f16* __restrict__ A, const f16* __restrict__ W,
                CT* __restrict__ C, int K, int lda, int ldc, int Nreal,
                long sAu, long sWu, long sCu)
{
    const int gx = gridDim.x, gy = gridDim.y;
    int bid = blockIdx.x + gx * (blockIdx.y + gy * blockIdx.z);
    const int nwg = gx * gy * gridDim.z;
    if ((nwg & 7) == 0)                  // XCD swizzle (bijective when nwg%8==0)
        bid = (bid & 7) * (nwg >> 3) + (bid >> 3);
    const int bx  = bid % gx;
    const int byz = bid / gx;
    const int by  = byz % gy;
    const int bz  = byz / gy;
    A += (long)bz * sAu;
    W += (long)bz * sWu;
    C += (long)bz * sCu;
    const int tm = bx * 256;
    const int tn = by * 256;

    __shared__ __attribute__((aligned(16))) f16 As[2][256 * 64];
    __shared__ __attribute__((aligned(16))) f16 Ws[2][256 * 64];

    const int tid  = threadIdx.x;
    const int wave = tid >> 6;
    const int lane = tid & 63;
    const int wm = (wave >> 2) * 128;              // 2 wave-rows
    const int wn = (wave & 3) * 64;                // 4 wave-cols
    const int srow = lane >> 3;
    const int scol = ((lane & 7) ^ srow) * 8;      // pre-swizzled global col
    const int mrow = lane & 15;
    const int kq   = (lane >> 4) * 8;
    const int swz  = (mrow & 7) << 3;

    f32x4 acc[8][4] = {};
    f16x8 wF[4], aF[4];

    // stage one half-tile (hq: 0=A rows 0-127, 1=A 128-255, 2=W 0-127, 3=W 128-255)
    // of K-tile kt into buffer b: 2 async16 per thread.
    auto stageH = [&](int b, int kt, int hq) {
        const int kk = kt << 6;
        const int rb0 = (hq & 1) * 128;
#pragma unroll
        for (int t2 = 0; t2 < 2; t2++) {
            const int rb = rb0 + t2 * 64 + wave * 8;   // wave-uniform LDS base
            if (hq < 2) async16(A + (long)(tm + rb + srow) * lda + (kk + scol), &As[b][rb * 64]);
            else        async16(W + (long)(tn + rb + srow) * K   + (kk + scol), &Ws[b][rb * 64]);
        }
    };
    auto ldW = [&](int b, int c) {
        const int cc = (c * 32 + kq) ^ swz;
#pragma unroll
        for (int j = 0; j < 4; j++)
            wF[j] = *(const f16x8*)&Ws[b][(wn + j * 16 + mrow) * 64 + cc];
    };
    auto ldA = [&](int b, int c, int ih) {
        const int cc = (c * 32 + kq) ^ swz;
#pragma unroll
        for (int i = 0; i < 4; i++)
            aF[i] = *(const f16x8*)&As[b][(wm + ih * 64 + i * 16 + mrow) * 64 + cc];
    };
    auto mma = [&](int ih) {
        __builtin_amdgcn_s_setprio(1);
#pragma unroll
        for (int i = 0; i < 4; i++)
#pragma unroll
            for (int j = 0; j < 4; j++)
                acc[ih * 4 + i][j] = __builtin_amdgcn_mfma_f32_16x16x32_f16(aF[i], wF[j], acc[ih * 4 + i][j], 0, 0, 0);
        __builtin_amdgcn_s_setprio(0);
    };

    const int nk = K >> 6;
    // prologue: tile 0 fully staged (8 loads/thread)
#pragma unroll
    for (int h = 0; h < 4; h++) stageH(0, 0, h);

    for (int t = 0; t < nk; t++) {
        const int b  = t & 1;
        const bool pf = (t + 1 < nk);
        // ---- phase 0 (c=0, ih=0): buffer switch
        if (pf) stageH(b ^ 1, t + 1, 0);
        if (pf) VMW2(); else VMW0();     // tile t resident; newest 2 stay in flight
        BAR();
        ldW(b, 0); ldA(b, 0, 0);
        mma(0);
        BAR();
        // ---- phase 1 (c=0, ih=1)
        ldA(b, 0, 1);
        if (pf) stageH(b ^ 1, t + 1, 1);
        BAR();
        mma(1);
        BAR();
        // ---- phase 2 (c=1, ih=0)
        ldW(b, 1); ldA(b, 1, 0);
        if (pf) stageH(b ^ 1, t + 1, 2);
        BAR();
        mma(0);
        BAR();
        // ---- phase 3 (c=1, ih=1)
        ldA(b, 1, 1);
        if (pf) stageH(b ^ 1, t + 1, 3);
        BAR();
        mma(1);
        BAR();
    }

    const int rrow = (lane >> 4) * 4;   // C/D: col = lane&15, row = (lane>>4)*4 + r
#pragma unroll
    for (int i = 0; i < 8; i++)
#pragma unroll
        for (int j = 0; j < 4; j++) {
            const int col = tn + wn + j * 16 + mrow;
            if (col < Nreal)
#pragma unroll
                for (int r = 0; r < 4; r++)
                    C[(long)(tm + wm + i * 16 + rrow + r) * ldc + col] = (CT)acc[i][j][r];
        }
}

// ---------------- 2-phase MFMA f16 GEMM (ctxW): BM=256, BN template ----------
template <typename CT, int BN, int WM, int WN>
__global__ __launch_bounds__(512, 2)
void mfma_gemm2(const f16* __restrict__ A, const f16* __restrict__ W,
                CT* __restrict__ C, int K, int lda, int ldc, int Nreal,
                long sAu, long sWu, long sCu)
{
    constexpr int MI = 256 / WM / 16;    // m-fragments per wave
    const int gx = gridDim.x, gy = gridDim.y;
    int bid = blockIdx.x + gx * (blockIdx.y + gy * blockIdx.z);
    const int nwg = gx * gy * gridDim.z;
    if ((nwg & 7) == 0)
        bid = (bid & 7) * (nwg >> 3) + (bid >> 3);
    const int bx  = bid % gx;
    const int byz = bid / gx;
    const int by  = byz % gy;
    const int bz  = byz / gy;
    A += (long)bz * sAu;
    W += (long)bz * sWu;
    C += (long)bz * sCu;
    const int tm = bx * 256;
    const int tn = by * BN;

    __shared__ __attribute__((aligned(16))) f16 As[2][256 * 64];
    __shared__ __attribute__((aligned(16))) f16 Ws[2][BN * 64];

    const int tid  = threadIdx.x;
    const int wave = tid >> 6;
    const int lane = tid & 63;
    const int wm = (wave / WN) * (256 / WM);
    const int wn = (wave % WN) * (BN / WN);
    const int srow = lane >> 3;
    const int scol = ((lane & 7) ^ srow) * 8;
    const int mrow = lane & 15;
    const int kq   = (lane >> 4) * 8;
    const int swz  = (mrow & 7) << 3;

    f32x4 acc[MI][4] = {};

    auto stage = [&](int b, int kk) {
#pragma unroll
        for (int t = 0; t < 4; t++) {
            const int rb = t * 64 + wave * 8;
            async16(A + (long)(tm + rb + srow) * lda + (kk + scol), &As[b][rb * 64]);
        }
#pragma unroll
        for (int t = 0; t < BN / 64; t++) {
            const int rb = t * 64 + wave * 8;
            async16(W + (long)(tn + rb + srow) * K + (kk + scol), &Ws[b][rb * 64]);
        }
    };
    auto compute = [&](int b) {
#pragma unroll
        for (int c = 0; c < 2; c++) {
            const int cc = (c * 32 + kq) ^ swz;
            f16x8 aF[MI], wF[4];
#pragma unroll
            for (int i = 0; i < MI; i++)
                aF[i] = *(const f16x8*)&As[b][(wm + i * 16 + mrow) * 64 + cc];
#pragma unroll
            for (int j = 0; j < 4; j++)
                wF[j] = *(const f16x8*)&Ws[b][(wn + j * 16 + mrow) * 64 + cc];
#pragma unroll
            for (int i = 0; i < MI; i++)
#pragma unroll
                for (int j = 0; j < 4; j++)
                    acc[i][j] = __builtin_amdgcn_mfma_f32_16x16x32_f16(aF[i], wF[j], acc[i][j], 0, 0, 0);
        }
    };

    stage(0, 0);
    int bsel = 0;
    const int nk = K >> 6;
    for (int s = 0; s < nk; s++) {
        __syncthreads();
        if (s + 1 < nk) stage(bsel ^ 1, (s + 1) << 6);
        compute(bsel);
        bsel ^= 1;
    }
    const int rrow = (lane >> 4) * 4;
#pragma unroll
    for (int i = 0; i < MI; i++)
#pragma unroll
        for (int j = 0; j < 4; j++) {
            const int col = tn + wn + j * 16 + mrow;
            if (col < Nreal)
#pragma unroll
                for (int r = 0; r < 4; r++)
                    C[(long)(tm + wm + i * 16 + rrow + r) * ldc + col] = (CT)acc[i][j][r];
        }
}

// ---------------- small MFMA f16 GEMM (vx only): 128x128 tiles, 256 thr -------
template <typename CT>
__global__ __launch_bounds__(256)
void mfma_gemm(const f16* __restrict__ A, const f16* __restrict__ W,
               CT* __restrict__ C, int K, int lda, int ldc,
               long sAu, long sWu, long sCu)
{
    A += (long)blockIdx.z * sAu;
    W += (long)blockIdx.z * sWu;
    C += (long)blockIdx.z * sCu;
    const int tm = blockIdx.x * 128;
    const int tn = blockIdx.y * 128;
    __shared__ __attribute__((aligned(16))) f16 As[2][128 * 64];
    __shared__ __attribute__((aligned(16))) f16 Ws[2][128 * 64];
    const int tid  = threadIdx.x;
    const int wave = tid >> 6;
    const int lane = tid & 63;
    const int wm = (wave >> 1) * 64;
    const int wn = (wave & 1) * 64;
    const int srow = lane >> 3;
    const int scol = ((lane & 7) ^ srow) * 8;
    const int mrow = lane & 15;
    const int kq   = (lane >> 4) * 8;
    const int swz  = (mrow & 7) << 3;

    f32x4 acc[4][4] = {};

    auto stage = [&](int b, int kk) {
#pragma unroll
        for (int t = 0; t < 4; t++) {
            const int rbase = t * 32 + wave * 8;
            async16(A + (long)(tm + rbase + srow) * lda + (kk + scol), &As[b][rbase * 64]);
            async16(W + (long)(tn + rbase + srow) * K   + (kk + scol), &Ws[b][rbase * 64]);
        }
    };
    auto compute = [&](int b) {
#pragma unroll
        for (int c = 0; c < 2; c++) {
            const int cc = (c * 32 + kq) ^ swz;
            f16x8 aF[4], wF[4];
#pragma unroll
            for (int i = 0; i < 4; i++)
                aF[i] = *(const f16x8*)&As[b][(wm + i * 16 + mrow) * 64 + cc];
#pragma unroll
            for (int j = 0; j < 4; j++)
                wF[j] = *(const f16x8*)&Ws[b][(wn + j * 16 + mrow) * 64 + cc];
#pragma unroll
            for (int i = 0; i < 4; i++)
#pragma unroll
                for (int j = 0; j < 4; j++)
                    acc[i][j] = __builtin_amdgcn_mfma_f32_16x16x32_f16(aF[i], wF[j], acc[i][j], 0, 0, 0);
        }
    };

    stage(0, 0);
    int bsel = 0;
    const int nk = K >> 6;
    for (int s = 0; s < nk; s++) {
        __syncthreads();
        if (s + 1 < nk) stage(bsel ^ 1, (s + 1) << 6);
        compute(bsel);
        bsel ^= 1;
    }
    const int rrow = (lane >> 4) * 4;
#pragma unroll
    for (int i = 0; i < 4; i++)
#pragma unroll
        for (int j = 0; j < 4; j++)
#pragma unroll
            for (int r = 0; r < 4; r++)
                C[(long)(tm + wm + i * 16 + rrow + r) * ldc + (tn + wn + j * 16 + mrow)] = (CT)acc[i][j][r];
}

// ---------------- fused fp32 GEMM (top-k critical): q = hs@Wq (z<6), kx = x@Wk (z==6)
__global__ __launch_bounds__(256)
void sgemm_fused(const float* __restrict__ hs, const float* __restrict__ Wq,
                 const float* __restrict__ x, const float* __restrict__ Wk,
                 float* __restrict__ q, float* __restrict__ kx)
{
    const int z = blockIdx.z;
    const float* A; const float* W; float* C; int lda, ldc;
    if (z < 6) { A = hs + z * 600; W = Wq + (long)z * 38400; C = q + z * 64; lda = 3600; ldc = 384; }
    else       { A = x;            W = Wk;                   C = kx;         lda = 600;  ldc = 64;  }
    const int K = 600;
    const int tm = blockIdx.x * 64;
    __shared__ __attribute__((aligned(16))) float AsT[16][64];   // k-major
    __shared__ __attribute__((aligned(16))) float Ws[16][64];
    const int t = threadIdx.x;
    const int arow = t >> 2, akc = (t & 3) * 4;
    const int wkw = t >> 4, wn = (t & 15) * 4;
    const int tx = t & 15, ty = t >> 4;

    float4 aR, wR;
    const float* Arow = A + (long)(tm + arow) * lda;
    auto loadA = [&](int kk) {
        const int k0 = kk + akc;
        const float* p = Arow + k0;
        if (k0 + 3 < K) aR = *(const float4*)p;
        else {
            aR.x = (k0 + 0 < K) ? p[0] : 0.f; aR.y = (k0 + 1 < K) ? p[1] : 0.f;
            aR.z = (k0 + 2 < K) ? p[2] : 0.f; aR.w = (k0 + 3 < K) ? p[3] : 0.f;
        }
    };
    auto loadW = [&](int kk) {
        const int k = kk + wkw;
        if (k < K) wR = *(const float4*)(W + (long)k * 64 + wn);
        else       wR = float4{0.f, 0.f, 0.f, 0.f};
    };
    loadA(0); loadW(0);
    float acc[4][4] = {{0.f}};
    const int NS = 38;
    for (int s = 0; s < NS; s++) {
        __syncthreads();
        AsT[akc + 0][arow] = aR.x; AsT[akc + 1][arow] = aR.y;
        AsT[akc + 2][arow] = aR.z; AsT[akc + 3][arow] = aR.w;
        *(float4*)&Ws[wkw][wn] = wR;
        __syncthreads();
        if (s + 1 < NS) { loadA((s + 1) * 16); loadW((s + 1) * 16); }
#pragma unroll
        for (int k = 0; k < 16; k++) {
            const float4 av = *(const float4*)&AsT[k][ty * 4];
            const float4 wv = *(const float4*)&Ws[k][tx * 4];
            acc[0][0] += av.x * wv.x; acc[0][1] += av.x * wv.y; acc[0][2] += av.x * wv.z; acc[0][3] += av.x * wv.w;
            acc[1][0] += av.y * wv.x; acc[1][1] += av.y * wv.y; acc[1][2] += av.y * wv.z; acc[1][3] += av.y * wv.w;
            acc[2][0] += av.z * wv.x; acc[2][1] += av.z * wv.y; acc[2][2] += av.z * wv.z; acc[2][3] += av.z * wv.w;
            acc[3][0] += av.w * wv.x; acc[3][1] += av.w * wv.y; acc[3][2] += av.w * wv.z; acc[3][3] += av.w * wv.w;
        }
    }
#pragma unroll
    for (int r = 0; r < 4; r++)
#pragma unroll
        for (int c = 0; c < 4; c++)
            C[(long)(tm + ty * 4 + r) * ldc + tx * 4 + c] = acc[r][c];
}

// -------- weight transpose+convert with self-padding:
__global__ __launch_bounds__(256)
void wtrans(const float* __restrict__ src, f16* __restrict__ dst,
            int K, int N, int Kp, int Np, int ldd, long sSrc, long sDst)
{
    src += (long)blockIdx.z * sSrc;
    dst += (long)blockIdx.z * sDst;
    __shared__ float tile[32][33];
    const int tK = blockIdx.x * 32, tN = blockIdx.y * 32;
    const int tx = threadIdx.x & 31, ty = threadIdx.x >> 5;
#pragma unroll
    for (int i = 0; i < 4; i++) {
        const int k = tK + ty + i * 8, n = tN + tx;
        tile[ty + i * 8][tx] = (k < K && n < N) ? src[(long)k * N + n] : 0.f;
    }
    __syncthreads();
#pragma unroll
    for (int i = 0; i < 4; i++) {
        const int n = tN + ty + i * 8, k = tK + tx;
        if (n < Np && k < Kp) dst[(long)n * ldd + k] = (f16)tile[tx][ty + i * 8];
    }
}

// ---------------- elementwise kernels -----------------------------------------
__global__ void xconv_kernel(const float* __restrict__ x, f16* __restrict__ xf, long n)
{
    const long i = (long)blockIdx.x * 256 + threadIdx.x;
    if (i >= n) return;
    const long b = i / 640;
    const int c = (int)(i - b * 640);
    xf[i] = (f16)(c < 600 ? x[b * 600 + c] : 0.f);
}

__global__ void s0_kernel(const float* __restrict__ q, const float* __restrict__ kx,
                          float* __restrict__ s0, int n)
{
    const int i = blockIdx.x * 256 + threadIdx.x;
    if (i >= n) return;
    const int b = i / 6;
    const float* qp = q + (long)i * 64;
    const float* kp = kx + (long)b * 64;
    float s = 0.f;
#pragma unroll
    for (int k = 0; k < 64; k++) s += qp[k] * kp[k];
    s0[i] = s * 0.125f;    // / sqrt(64)
}

__global__ void mask_kernel(const float* __restrict__ s0, float* __restrict__ mask,
                            float* __restrict__ alpha, int Bc)
{
    const int b = blockIdx.x * 256 + threadIdx.x;
    if (b >= Bc) return;
    float v[6];
#pragma unroll
    for (int u = 0; u < 6; u++) v[u] = s0[b * 6 + u];
#pragma unroll
    for (int u = 0; u < 6; u++) {
        int rank = 0;
#pragma unroll
        for (int m = 0; m < 6; m++)
            rank += ((v[m] > v[u]) || (v[m] == v[u] && m < u)) ? 1 : 0;   // stable top-k
        const float mk = (rank < 4) ? 1.f : 0.f;
        mask[b * 6 + u] = mk;
        alpha[b * 6 + u] = mk / (1.f + __expf(-v[u]));
    }
}

__global__ void inputs_kernel(const float* __restrict__ vx, const float* __restrict__ hs,
                              const float* __restrict__ alpha, f16* __restrict__ icat, long n)
{   // icat (b,u,1024) = [alpha*vx(400) | hs(600) | 0(24)]
    const long i = (long)blockIdx.x * 256 + threadIdx.x;
    if (i >= n) return;
    const int k = (int)(i & 1023);
    const long bu = i >> 10;
    float v;
    if (k < 400)       v = alpha[bu] * vx[(bu / 6) * 512 + k];
    else if (k < 1000) v = hs[bu * 600 + (k - 400)];
    else               v = 0.f;
    icat[i] = (f16)v;
}

__device__ __forceinline__ float tanh_fast(float x) {
    x = fminf(20.f, fmaxf(-20.f, x));
    const float e = __expf(2.f * x);
    return (e - 1.f) / (e + 1.f);
}

__global__ void lstm_kernel(const f16* __restrict__ pre, const float* __restrict__ cs,
                            const float* __restrict__ mask, float* __restrict__ cs_out,
                            f16* __restrict__ hbf, long n)   // n = Bc*6*640
{
    const long i = (long)blockIdx.x * 256 + threadIdx.x;
    if (i >= n) return;
    const long bu = i / 640;
    const int h = (int)(i - bu * 640);
    if (h >= 600) { hbf[i] = (f16)0.f; return; }   // zero K-pad for next GEMM
    const f16* p = pre + bu * 2432;
    const float ig = 1.f / (1.f + __expf(-(float)p[h]));
    const float fg = 1.f / (1.f + __expf(-(float)p[600 + h]));
    const float og = 1.f / (1.f + __expf(-(float)p[1200 + h]));
    const float g  = tanh_fast((float)p[1800 + h]);
    const float cold = cs[bu * 600 + h];
    const float c = cold * fg + ig * g;
    cs_out[bu * 600 + h] = (mask[bu] != 0.f) ? c : cold;
    hbf[i] = (f16)(og * tanh_fast(c));
}

__global__ __launch_bounds__(256)
void attn_kernel(const f16* __restrict__ out2, const float* __restrict__ mask,
                 f16* __restrict__ ctx)
{   // out2 (b,m,2688) f16: [cv 0:2400 | ck 2400:2528 | cq 2528:2656 | pad]
    // ctx (b,u,2432): cols [2400,2432) zero-filled (K-pad for ctx@Wco GEMM)
    const long b = blockIdx.x;
    __shared__ float sck[6][128];
    __shared__ float scq[6][128];
    __shared__ float sp[4][6][6];
    const int t = threadIdx.x;
#pragma unroll
    for (int m = 0; m < 6; m++) {
        const f16* row = out2 + (b * 6 + m) * 2688;
        if (t < 128) sck[m][t] = (float)row[2400 + t];
        else         scq[m][t - 128] = (float)row[2528 + (t - 128)];
    }
    __syncthreads();
    if (t < 144) {
        const int h = t / 36, u = (t / 6) % 6, m = t % 6;
        float s = 0.f;
#pragma unroll
        for (int k = 0; k < 32; k++) s += scq[u][h * 32 + k] * sck[m][h * 32 + k];
        sp[h][u][m] = s * 0.1767766952966369f;   // 1/sqrt(32)
    }
    __syncthreads();
    if (t < 24) {
        const int h = t / 6, u = t % 6;
        float mx = sp[h][u][0];
#pragma unroll
        for (int m = 1; m < 6; m++) mx = fmaxf(mx, sp[h][u][m]);
        float e[6], sum = 0.f;
#pragma unroll
        for (int m = 0; m < 6; m++) { e[m] = __expf(sp[h][u][m] - mx); sum += e[m]; }
        const float sc = mask[b * 6 + u] / sum;
#pragma unroll
        for (int m = 0; m < 6; m++) sp[h][u][m] = e[m] * sc;
    }
    __syncthreads();
    for (int f = t; f < 2432; f += 256) {
        if (f < 2400) {
            const int h = f / 600;
            float cv[6];
#pragma unroll
            for (int m = 0; m < 6; m++) cv[m] = (float)out2[(b * 6 + m) * 2688 + f];
#pragma unroll
            for (int u = 0; u < 6; u++) {
                float s = 0.f;
#pragma unroll
                for (int m = 0; m < 6; m++) s += sp[h][u][m] * cv[m];
                ctx[(b * 6 + u) * 2432 + f] = (f16)s;
            }
        } else {
#pragma unroll
            for (int u = 0; u < 6; u++) ctx[(b * 6 + u) * 2432 + f] = (f16)0.f;
        }
    }
}

__global__ void epi_kernel(const f16* __restrict__ ctxW, const f16* __restrict__ hbf,
                           const float* __restrict__ hs, const float* __restrict__ mask,
                           float* __restrict__ hs_out, long n)   // n = Bc*3600
{
    const long i = (long)blockIdx.x * 256 + threadIdx.x;
    if (i >= n) return;
    const long bu = i / 600;
    const int h = (int)(i - bu * 600);
    hs_out[i] = (mask[bu] != 0.f) ? ((float)ctxW[bu * 640 + h] + (float)hbf[bu * 640 + h]) : hs[i];
}

// ---------------- host launcher ------------------------------------------------
static inline unsigned cdivu(long a, long b) { return (unsigned)((a + b - 1) / b); }

extern "C" void kernel_launch(void* const* d_in, const int* in_sizes, int n_in,
                              void* d_out, int out_size, void* d_ws, size_t ws_size,
                              hipStream_t stream)
{
    (void)in_sizes; (void)n_in; (void)out_size;
    const float* x    = (const float*)d_in[0];
    const float* hs   = (const float*)d_in[1];
    const float* cs   = (const float*)d_in[2];
    const float* Wk   = (const float*)d_in[3];
    const float* Wv   = (const float*)d_in[4];
    const float* Wq   = (const float*)d_in[5];
    const float* Wi2h = (const float*)d_in[6];
    const float* Wh2h = (const float*)d_in[7];
    const float* Wck  = (const float*)d_in[8];
    const float* Wcq  = (const float*)d_in[9];
    const float* Wcv  = (const float*)d_in[10];
    const float* Wco  = (const float*)d_in[11];
    float* hs_out = (float*)d_out;
    float* cs_out = hs_out + (long)4096 * 6 * 600;

    char* wsb = (char*)d_ws;
    size_t off = 0;
    auto alloc = [&](size_t bytes) -> char* {
        char* p = wsb + off;
        off += (bytes + 255) & ~(size_t)255;
        return p;
    };

    // f16 weights, (N,K) transposed, N padded to tile grid, K padded to x64:
    // W1T (2560,1024) [Wi2h;Wh2h], W2T (2816,640) [Wcv|Wck|Wcq|pad],
    // W3T (640,2432) [Wco], WvT (512,640) [Wv]
    f16* W1T = (f16*)alloc((size_t)6 * 2560 * 1024 * 2);
    f16* W2T = (f16*)alloc((size_t)6 * 2816 * 640 * 2);
    f16* W3T = (f16*)alloc((size_t)6 * 640 * 2432 * 2);
    f16* WvT = (f16*)alloc((size_t)512 * 640 * 2);

    // full-batch buffers (B=4096)
    f16*   xf   = (f16*)  alloc((size_t)4096 * 640 * 2);
    float* kx   = (float*)alloc((size_t)4096 * 64 * 4);
    float* vx   = (float*)alloc((size_t)4096 * 512 * 4);
    float* q    = (float*)alloc((size_t)4096 * 384 * 4);
    float* s0   = (float*)alloc((size_t)4096 * 6 * 4);
    float* alph = (float*)alloc((size_t)4096 * 6 * 4);
    float* mskv = (float*)alloc((size_t)4096 * 6 * 4);
    const size_t fixedbytes = off;

    // per-chunk activations (all f16):
    // perRow = icat 12288 + pre 29184 + hbf 7680 + out2 32256 = 81408 B
    const size_t perRow = 81408;
    int Bc = 4096;
    while (Bc > 256 && fixedbytes + (size_t)Bc * perRow + 16384 > ws_size) Bc >>= 1;

    f16* icat = (f16*)alloc((size_t)Bc * 6 * 1024 * 2);
    f16* pre  = (f16*)alloc((size_t)Bc * 6 * 2432 * 2);
    f16* hbf  = (f16*)alloc((size_t)Bc * 6 * 640 * 2);
    f16* out2 = (f16*)alloc((size_t)Bc * 6 * 2688 * 2);
    // overlays: ctx over dead pre (after LSTM); ctxW over dead out2 (after attn)
    f16* ctx  = pre;    // needs Bc*6*2432*2 <= Bc*6*2432*2  ok (exact)
    f16* ctxW = out2;   // needs Bc*6*640*2  <= Bc*6*2688*2  ok

    // ---- weights: transpose-convert with self-padding (no memset needed) ----
    wtrans<<<dim3(13, 80, 6), 256, 0, stream>>>(Wi2h, W1T,        400, 2400, 400, 2560, 1024, 960000L,  2621440L);
    wtrans<<<dim3(20, 80, 6), 256, 0, stream>>>(Wh2h, W1T + 400,  600, 2400, 624, 2560, 1024, 1440000L, 2621440L);
    wtrans<<<dim3(20, 75, 6), 256, 0, stream>>>(Wcv,  W2T,        600, 2400, 640, 2400, 640,  1440000L, 1802240L);
    wtrans<<<dim3(20, 4, 6),  256, 0, stream>>>(Wck,  W2T + (long)2400 * 640, 600, 128, 640, 128, 640, 76800L, 1802240L);
    wtrans<<<dim3(20, 9, 6),  256, 0, stream>>>(Wcq,  W2T + (long)2528 * 640, 600, 128, 640, 288, 640, 76800L, 1802240L);
    wtrans<<<dim3(76, 20, 6), 256, 0, stream>>>(Wco,  W3T,        2400, 600, 2432, 640, 2432, 1440000L, 1556480L);
    wtrans<<<dim3(20, 16, 1), 256, 0, stream>>>(Wv,   WvT,        600,  400, 640, 512, 640,  0L, 0L);

    // ---- full-batch score path (exact fp32 where top-k depends on it) ----
    xconv_kernel<<<cdivu((long)4096 * 640, 256), 256, 0, stream>>>(x, xf, (long)4096 * 640);
    sgemm_fused<<<dim3(64, 1, 7), 256, 0, stream>>>(hs, Wq, x, Wk, q, kx);
    mfma_gemm<float><<<dim3(32, 4, 1), 256, 0, stream>>>(xf, WvT, vx, 640, 640, 512, 0, 0, 0);
    s0_kernel<<<cdivu((long)4096 * 6, 256), 256, 0, stream>>>(q, kx, s0, 4096 * 6);
    mask_kernel<<<cdivu(4096, 256), 256, 0, stream>>>(s0, mskv, alph, 4096);

    for (int b0 = 0; b0 < 4096; b0 += Bc) {
        const float* hsc = hs + (long)b0 * 3600;
        const float* csc = cs + (long)b0 * 3600;
        float* hso = hs_out + (long)b0 * 3600;
        float* cso = cs_out + (long)b0 * 3600;

        inputs_kernel<<<cdivu((long)Bc * 6144, 256), 256, 0, stream>>>(
            vx + (long)b0 * 512, hsc, alph + (long)b0 * 6, icat, (long)Bc * 6144);
        // preact = [a*vx|hs] @ [Wi2h;Wh2h]   (f16 out), N 2432 padded to 2560, 8-phase
        mfma_gemm8<f16><<<dim3(Bc / 256, 10, 6), 512, 0, stream>>>(
            icat, W1T, pre, 1024, 6144, 14592, 2432, 1024, 2621440, 2432);
        lstm_kernel<<<cdivu((long)Bc * 3840, 256), 256, 0, stream>>>(
            pre, csc, mskv + (long)b0 * 6, cso, hbf, (long)Bc * 3840);
        // [cv|ck|cq] = h @ [Wcv|Wck|Wcq]   (f16 out), N 2688 padded to 2816, 8-phase
        mfma_gemm8<f16><<<dim3(Bc / 256, 11, 6), 512, 0, stream>>>(
            hbf, W2T, out2, 640, 3840, 16128, 2688, 640, 1802240, 2688);
        attn_kernel<<<Bc, 256, 0, stream>>>(out2, mskv + (long)b0 * 6, ctx);
        // ctxW = ctx @ Wco   (f16 out), N=640 exact with BN=128, 2-phase
        mfma_gemm2<f16, 128, 4, 2><<<dim3(Bc / 256, 5, 6), 512, 0, stream>>>(
            ctx, W3T, ctxW, 2432, 14592, 3840, 640, 2432, 1556480, 640);
        epi_kernel<<<cdivu((long)Bc * 3600, 256), 256, 0, stream>>>(
            ctxW, hbf, hsc, mskv + (long)b0 * 6, hso, (long)Bc * 3600);
    }
}